// Round 9
// baseline (835.326 us; speedup 1.0000x reference)
//
#include <hip/hip_runtime.h>

#define DIMN 128
#define NLAYERS 4
#define KP 136                 // padded k-stride for transposed W / Agg tiles (conflict-free b128)
#define WTSH (2 * DIMN * KP)   // shorts per combined prepped matrix (hi plane + lo plane)
#define WTL_SH (DIMN * DIMN)   // shorts per lo-plane matrix (global, fragment-contiguous)

// ---- binned counting-sort CSR parameters ----
#define BQL 9                  // log2(bucket width in nodes)
#define BUCKW 512              // nodes per bucket
#define BUCKCAP 10240          // edge capacity per bucket (mean 8192, +22 sigma)
#define BSCH 4096              // edges per binsort block
#define NBUK_MAX 256           // static LDS sizing (runtime NBUK = 196)

// degOut histogram partitioning: P node-partitions x C edge-chunks, partial arrays
#define HP_P 3
#define HP_C 48
#define HIST_BLOCKS (HP_P * HP_C)   // 144
#define HW_WORDS 16667              // ceil(ceil(N/2)/HP_P) packed words; 66,668 B LDS

typedef __attribute__((ext_vector_type(8))) short bf16x8;  // 8 bf16 = 4 VGPRs
typedef __attribute__((ext_vector_type(4))) float f32x4;

__device__ inline float bfu2f(unsigned int u) { return __uint_as_float(u << 16); }
__device__ inline unsigned short f2bf(float f) {
    unsigned int u = __float_as_uint(f);
    return (unsigned short)((u + 0x7fffu + ((u >> 16) & 1u)) >> 16);  // RTNE
}
__device__ inline float blo(unsigned int u) { return __uint_as_float(u << 16); }
__device__ inline float bhi(unsigned int u) { return __uint_as_float(u & 0xffff0000u); }

// lo-plane fragment-contiguous offset (round-8 correctness-proven): per (ks,ct) a 1KB
// block in exact per-lane read order -> each wave's bl load is one coalesced 1KB run.
__device__ __host__ inline int lo_off(int n, int k) {
    return ((((k >> 5) * 8 + (n >> 4)) * 16 + (n & 15)) * 4 + ((k >> 3) & 3)) * 8 + (k & 7);
}

// ---------------- pre kernel: degOut histogram partials + W prep (role split) ----------------
__global__ __launch_bounds__(256) void k_pre(const int* __restrict__ src,
                                             const float* __restrict__ We,
                                             const float* __restrict__ Wlayers,
                                             unsigned int* __restrict__ degOutP,  // [HP_C][W]
                                             short* __restrict__ wt,
                                             short* __restrict__ wtl, int N, int E) {
    __shared__ unsigned int hsm[HW_WORDS];
    int tid = threadIdx.x;
    int bid = blockIdx.x;

    if (bid < HIST_BLOCKS) {
        int c = bid / HP_P;
        int p = bid % HP_P;
        int W = (N + 1) / 2;                   // packed words for all nodes
        int w0 = p * HW_WORDS;
        int wn = min(HW_WORDS, W - w0);
        if (wn <= 0) return;
        int per = ((E + HP_C - 1) / HP_C + 3) & ~3;  // chunk size, multiple of 4
        int e0 = c * per;
        int e1 = min(e0 + per, E);
        if (e0 >= e1) {  // still must zero-fill our exclusive output range
            for (int i = tid; i < wn; i += 256) degOutP[(size_t)c * W + w0 + i] = 0u;
            return;
        }
        for (int i = tid; i < wn; i += 256) hsm[i] = 0u;
        __syncthreads();
        int nvec = (e1 - e0) >> 2;
        const int4* sv = (const int4*)(src + e0);
        for (int it = tid; it < nvec; it += 256) {
            int4 v = sv[it];
            int w;
            w = (v.x >> 1) - w0; if ((unsigned)w < (unsigned)wn) atomicAdd(&hsm[w], 1u << ((v.x & 1) << 4));
            w = (v.y >> 1) - w0; if ((unsigned)w < (unsigned)wn) atomicAdd(&hsm[w], 1u << ((v.y & 1) << 4));
            w = (v.z >> 1) - w0; if ((unsigned)w < (unsigned)wn) atomicAdd(&hsm[w], 1u << ((v.z & 1) << 4));
            w = (v.w >> 1) - w0; if ((unsigned)w < (unsigned)wn) atomicAdd(&hsm[w], 1u << ((v.w & 1) << 4));
        }
        for (int j = e0 + (nvec << 2) + tid; j < e1; j += 256) {
            int s = src[j];
            int w = (s >> 1) - w0;
            if ((unsigned)w < (unsigned)wn) atomicAdd(&hsm[w], 1u << ((s & 1) << 4));
        }
        __syncthreads();
        // exclusive flush: plain coalesced stores, no atomics
        for (int i = tid; i < wn; i += 256) degOutP[(size_t)c * W + w0 + i] = hsm[i];
        return;
    }

    // ------- wprep role: combined KP layout (embed + LDS hi staging) + frag lo layout -------
    {
        int m = bid - HIST_BLOCKS;  // 0 = embed, 1..4 = layers
        const float* Wm = (m == 0) ? We : Wlayers + (size_t)(m - 1) * DIMN * DIMN;
        short* o = wt + (size_t)m * WTSH;
        short* ol = wtl + (size_t)m * WTL_SH;
#pragma unroll
        for (int it = 0; it < 16; ++it) {
            int f = it * 1024 + tid * 4;
            float4 v = *(const float4*)(Wm + f);
            int k = f >> 7, n = f & 127;
            float vv[4] = {v.x, v.y, v.z, v.w};
#pragma unroll
            for (int j = 0; j < 4; ++j) {
                unsigned short hb = f2bf(vv[j]);
                float lo = vv[j] - bfu2f(hb);
                unsigned short lb = f2bf(lo);
                o[(n + j) * KP + k] = (short)hb;
                o[DIMN * KP + (n + j) * KP + k] = (short)lb;
                ol[lo_off(n + j, k)] = (short)lb;
            }
        }
    }
}

// ------- binsort: LDS counting-sort edges into 512-node dst buckets, coalesced flush -------
__global__ __launch_bounds__(256) void k_binsort(const int* __restrict__ src,
                                                 const int* __restrict__ dst,
                                                 int* __restrict__ gcur,
                                                 int2* __restrict__ pairs,
                                                 int E, int NBUK) {
    __shared__ int cnt[NBUK_MAX];
    __shared__ int bofs[NBUK_MAX];
    __shared__ int gof[NBUK_MAX];
    __shared__ int scan_s[256];
    __shared__ int2 stg[BSCH];       // 32 KB
    int tid = threadIdx.x;
    int e0 = blockIdx.x * BSCH;
    int n = min(BSCH, E - e0);
    if (n <= 0) return;
    cnt[tid] = 0;
    __syncthreads();

    int nv = n >> 2;
    const int4* dv4 = (const int4*)(dst + e0);
    for (int it = tid; it < nv; it += 256) {
        int4 d = dv4[it];
        atomicAdd(&cnt[d.x >> BQL], 1);
        atomicAdd(&cnt[d.y >> BQL], 1);
        atomicAdd(&cnt[d.z >> BQL], 1);
        atomicAdd(&cnt[d.w >> BQL], 1);
    }
    for (int j = (nv << 2) + tid; j < n; j += 256) {
        atomicAdd(&cnt[dst[e0 + j] >> BQL], 1);
    }
    __syncthreads();

    // inclusive Hillis-Steele scan over 256 (NBUK <= 256)
    int myc = cnt[tid];
    scan_s[tid] = myc;
    __syncthreads();
    for (int off = 1; off < 256; off <<= 1) {
        int x = scan_s[tid];
        if (tid >= off) x += scan_s[tid - off];
        __syncthreads();
        scan_s[tid] = x;
        __syncthreads();
    }
    bofs[tid] = scan_s[tid] - myc;        // exclusive local prefix
    gof[tid] = (myc > 0 && tid < NBUK) ? atomicAdd(&gcur[tid], myc) : 0;
    cnt[tid] = 0;                          // reuse as local cursor
    __syncthreads();

    // stage pass: place edges bucket-sorted in LDS
    const int4* sv4 = (const int4*)(src + e0);
    for (int it = tid; it < nv; it += 256) {
        int4 d = dv4[it];
        int4 s = sv4[it];
        int b, p;
        b = d.x >> BQL; p = bofs[b] + atomicAdd(&cnt[b], 1); stg[p] = make_int2(s.x, d.x);
        b = d.y >> BQL; p = bofs[b] + atomicAdd(&cnt[b], 1); stg[p] = make_int2(s.y, d.y);
        b = d.z >> BQL; p = bofs[b] + atomicAdd(&cnt[b], 1); stg[p] = make_int2(s.z, d.z);
        b = d.w >> BQL; p = bofs[b] + atomicAdd(&cnt[b], 1); stg[p] = make_int2(s.w, d.w);
    }
    for (int j = (nv << 2) + tid; j < n; j += 256) {
        int d = dst[e0 + j], s = src[e0 + j];
        int b = d >> BQL;
        int p = bofs[b] + atomicAdd(&cnt[b], 1);
        stg[p] = make_int2(s, d);
    }
    __syncthreads();

    // flush: consecutive i within a bucket -> consecutive global positions (coalesced runs)
    for (int i = tid; i < n; i += 256) {
        int2 pr = stg[i];
        int b = pr.y >> BQL;
        int go = gof[b] + (i - bofs[b]);
        if (go < BUCKCAP) pairs[(size_t)b * BUCKCAP + go] = pr;
    }
}

// ------- build: per-bucket local counting sort -> csr (sorted src), rowptr, deg -------
__global__ __launch_bounds__(256) void k_build(const int2* __restrict__ pairs,
                                               const int* __restrict__ gcur,
                                               int* __restrict__ csr,
                                               int* __restrict__ rowptr,
                                               int* __restrict__ deg, int N) {
    int b = blockIdx.x;
    int tid = threadIdx.x;
    int cntb = gcur[b];
    if (cntb > BUCKCAP) cntb = BUCKCAP;
    __shared__ int c[BUCKW];
    __shared__ int pf[BUCKW];
    c[tid] = 0; c[tid + 256] = 0;
    __syncthreads();
    const int2* bp = pairs + (size_t)b * BUCKCAP;
    for (int i = tid; i < cntb; i += 256) atomicAdd(&c[bp[i].y & (BUCKW - 1)], 1);
    __syncthreads();
    pf[tid] = c[tid]; pf[tid + 256] = c[tid + 256];
    __syncthreads();
    // inclusive scan over 512 with 256 threads (double-sync Hillis-Steele)
    for (int off = 1; off < BUCKW; off <<= 1) {
        int i0 = tid, i1 = tid + 256;
        int v0 = pf[i0] + ((i0 >= off) ? pf[i0 - off] : 0);
        int v1 = pf[i1] + ((i1 >= off) ? pf[i1 - off] : 0);
        __syncthreads();
        pf[i0] = v0; pf[i1] = v1;
        __syncthreads();
    }
    {   // exclusive prefix in pf; emit rowptr/deg; reset c as cursor
        int i0 = tid, i1 = tid + 256;
        int c0 = c[i0], c1 = c[i1];
        int ex0 = pf[i0] - c0, ex1 = pf[i1] - c1;
        pf[i0] = ex0; pf[i1] = ex1;
        int gn0 = (b << BQL) + i0, gn1 = (b << BQL) + i1;
        if (gn0 < N) { rowptr[gn0] = b * BUCKCAP + ex0; deg[gn0] = c0; }
        if (gn1 < N) { rowptr[gn1] = b * BUCKCAP + ex1; deg[gn1] = c1; }
        c[i0] = 0; c[i1] = 0;
    }
    __syncthreads();
    int* cb = csr + (size_t)b * BUCKCAP;
    for (int i = tid; i < cntb; i += 256) {
        int2 p = bp[i];
        int ld = p.y & (BUCKW - 1);
        int pos = pf[ld] + atomicAdd(&c[ld], 1);
        cb[pos] = p.x;   // random 4B within ~40KB L2-resident window
    }
}

// ---------------- norms: deg (in) direct; degOut = sum of histogram partials ----------------
__global__ __launch_bounds__(256) void k_norms(const int* __restrict__ deg,
                                               const unsigned int* __restrict__ degOutP,
                                               float* __restrict__ norm_d,
                                               float* __restrict__ norm_s, int N) {
    int i = blockIdx.x * 256 + threadIdx.x;  // one packed word = 2 nodes per thread
    int W = (N + 1) / 2;
    if (i < W) {
        unsigned s0 = 0, s1 = 0;
#pragma unroll 8
        for (int c = 0; c < HP_C; ++c) {
            unsigned v = degOutP[(size_t)c * W + i];
            s0 += v & 0xffffu;
            s1 += v >> 16;
        }
        int n0 = 2 * i, n1 = 2 * i + 1;
        norm_s[n0] = rsqrtf(fmaxf((float)s0, 1.0f));
        norm_d[n0] = rsqrtf(fmaxf((float)deg[n0], 1.0f));
        if (n1 < N) {
            norm_s[n1] = rsqrtf(fmaxf((float)s1, 1.0f));
            norm_d[n1] = rsqrtf(fmaxf((float)deg[n1], 1.0f));
        }
    }
}

// ---- MFMA GEMM (embed): f32 A, 3-term bf16 split; full W in LDS; 512-thread/8-wave blocks ----
// (round-7 proven version, untouched)
__global__ __launch_bounds__(512) void k_gemm_f32(const float* __restrict__ A,
                                                  const short* __restrict__ Wt,
                                                  const float* __restrict__ bg,
                                                  float* __restrict__ tgt,
                                                  const float* __restrict__ norm_s,
                                                  unsigned short* __restrict__ Hs, int N) {
    __shared__ short Wl[WTSH];        // 69,632 B
    __shared__ float bias_s[DIMN];
    int tid = threadIdx.x;
    {
        const uint4* g = (const uint4*)Wt;
        uint4* l = (uint4*)Wl;
#pragma unroll
        for (int it = 0; it < 9; ++it) {
            int ix = it * 512 + tid;
            if (ix < WTSH / 8) l[ix] = g[ix];
        }
        if (tid < DIMN) bias_s[tid] = bg[tid];
    }
    __syncthreads();

    int lane = tid & 63;
    int wv = tid >> 6;                 // 0..7
    int quad = lane >> 4;
    int l15 = lane & 15;
    int row0 = blockIdx.x * 256 + wv * 32;

    f32x4 acc[2][8];
#pragma unroll
    for (int s = 0; s < 2; ++s)
#pragma unroll
        for (int ct = 0; ct < 8; ++ct) acc[s][ct] = (f32x4){0.f, 0.f, 0.f, 0.f};

    for (int ks = 0; ks < 4; ++ks) {
        int kb = ks * 32 + quad * 8;
        bf16x8 ah[2], al[2];
#pragma unroll
        for (int s = 0; s < 2; ++s) {
            int r = row0 + s * 16 + l15;
            if (r > N - 1) r = N - 1;
            const float* ap = A + (size_t)r * DIMN + kb;
            float4 p = *(const float4*)ap;
            float4 q = *(const float4*)(ap + 4);
            float fv[8] = {p.x, p.y, p.z, p.w, q.x, q.y, q.z, q.w};
#pragma unroll
            for (int j = 0; j < 8; ++j) {
                unsigned short hb = f2bf(fv[j]);
                ah[s][j] = (short)hb;
                al[s][j] = (short)f2bf(fv[j] - bfu2f(hb));
            }
        }
#pragma unroll
        for (int ct = 0; ct < 8; ++ct) {
            const short* bp = Wl + (ct * 16 + l15) * KP + kb;
            bf16x8 bh = *(const bf16x8*)bp;
            bf16x8 bl = *(const bf16x8*)(bp + DIMN * KP);
#pragma unroll
            for (int s = 0; s < 2; ++s) {
                acc[s][ct] = __builtin_amdgcn_mfma_f32_16x16x32_bf16(ah[s], bh, acc[s][ct], 0, 0, 0);
                acc[s][ct] = __builtin_amdgcn_mfma_f32_16x16x32_bf16(al[s], bh, acc[s][ct], 0, 0, 0);
                acc[s][ct] = __builtin_amdgcn_mfma_f32_16x16x32_bf16(ah[s], bl, acc[s][ct], 0, 0, 0);
            }
        }
    }

#pragma unroll
    for (int s = 0; s < 2; ++s) {
        int rbase = row0 + s * 16 + quad * 4;
        float ns[4];
#pragma unroll
        for (int rj = 0; rj < 4; ++rj) {
            int row = rbase + rj;
            ns[rj] = (row < N) ? norm_s[row] : 0.f;
        }
#pragma unroll
        for (int ct = 0; ct < 8; ++ct) {
            int col = ct * 16 + l15;
            float bv = bias_s[col];
#pragma unroll
            for (int rj = 0; rj < 4; ++rj) {
                int row = rbase + rj;
                if (row < N) {
                    float o = acc[s][ct][rj] + bv;
                    __builtin_nontemporal_store(o, &tgt[(size_t)row * DIMN + col]);
                    Hs[(size_t)row * DIMN + col] = f2bf(o * ns[rj]);
                }
            }
        }
    }
}

// ===== fused layer kernel: per-wave SpMM aggregation into LDS + MFMA GEMM + epilogue =====
// 512 threads / 8 waves / 128 rows. Each wave aggregates its own 16 nodes (proven spmm
// inner loop -> bf16 into KP-padded LDS tile), then immediately MFMAs them (hi-plane W
// from LDS, lo-plane from frag-contiguous global). Wave reads back only rows it wrote ->
// no barrier between phases; waves pipeline independently (gather || MFMA across the CU).
// HsIn/HsOut are DIFFERENT buffers (double-buffered across layers: in-kernel RAW hazard).
__global__ __launch_bounds__(512) void k_layer(const unsigned int* __restrict__ HsIn,
                                               const int* __restrict__ csr,
                                               const int* __restrict__ rowptr,
                                               const int* __restrict__ deg,
                                               const float* __restrict__ norm_d,
                                               const short* __restrict__ Wt,   // combined; hi = first DIMN*KP
                                               const short* __restrict__ Wtl,  // lo frag-contiguous
                                               const float* __restrict__ bg,
                                               const float* __restrict__ Hres,
                                               float* __restrict__ tgt,
                                               const float* __restrict__ norm_s,
                                               unsigned short* __restrict__ HsOut,
                                               int N) {
    __shared__ short Wl[DIMN * KP];        // 34,816 B  (hi plane)
    __shared__ short Ag[128 * KP];         // 34,816 B  (aggregated rows, bf16, KP pad)
    __shared__ float bias_s[DIMN];
    int tid = threadIdx.x;
    {
        const uint4* g4 = (const uint4*)Wt;  // hi plane is the first DIMN*KP shorts
        uint4* l4 = (uint4*)Wl;
#pragma unroll
        for (int it = 0; it < 5; ++it) {
            int ix = it * 512 + tid;
            if (ix < (DIMN * KP) / 8) l4[ix] = g4[ix];
        }
        if (tid < DIMN) bias_s[tid] = bg[tid];
    }
    __syncthreads();

    int lane = tid & 63;
    int wv = tid >> 6;        // 0..7
    int quad = lane >> 4;
    int l15 = lane & 15;
    int row0 = blockIdx.x * 128;

    // ---------- phase 1: aggregate this wave's 16 nodes ----------
    {
        int g = lane >> 5;
        int l5 = lane & 31;
        const uint2* H2 = (const uint2*)HsIn;
        for (int i = 0; i < 16; ++i) {
            int node = row0 + wv * 16 + i;
            float4 acc = make_float4(0.f, 0.f, 0.f, 0.f);
            if (node < N) {
                int cnt = deg[node];
                const int* base = csr + rowptr[node];
                int emain = cnt & ~7;
                int e = 0;
                for (; e < emain; e += 8) {  // 4 gathers in flight per lane
                    int s0 = base[e + g];
                    int s1 = base[e + 2 + g];
                    int s2 = base[e + 4 + g];
                    int s3 = base[e + 6 + g];
                    uint2 h0 = H2[(size_t)s0 * 32 + l5];
                    uint2 h1 = H2[(size_t)s1 * 32 + l5];
                    uint2 h2 = H2[(size_t)s2 * 32 + l5];
                    uint2 h3 = H2[(size_t)s3 * 32 + l5];
                    acc.x += blo(h0.x); acc.y += bhi(h0.x);
                    acc.z += blo(h0.y); acc.w += bhi(h0.y);
                    acc.x += blo(h1.x); acc.y += bhi(h1.x);
                    acc.z += blo(h1.y); acc.w += bhi(h1.y);
                    acc.x += blo(h2.x); acc.y += bhi(h2.x);
                    acc.z += blo(h2.y); acc.w += bhi(h2.y);
                    acc.x += blo(h3.x); acc.y += bhi(h3.x);
                    acc.z += blo(h3.y); acc.w += bhi(h3.y);
                }
                for (; e < cnt; e += 2) {    // tail
                    int ee = e + g;
                    int sc = base[min(ee, cnt - 1)];
                    uint2 hv = H2[(size_t)sc * 32 + l5];
                    if (ee < cnt) {
                        acc.x += blo(hv.x); acc.y += bhi(hv.x);
                        acc.z += blo(hv.y); acc.w += bhi(hv.y);
                    }
                }
            }
            acc.x += __shfl_xor(acc.x, 32);
            acc.y += __shfl_xor(acc.y, 32);
            acc.z += __shfl_xor(acc.z, 32);
            acc.w += __shfl_xor(acc.w, 32);
            if (g == 0) {
                float nd = (node < N) ? norm_d[node] : 0.f;
                unsigned long long p =
                    (unsigned long long)((unsigned)f2bf(acc.x * nd) | ((unsigned)f2bf(acc.y * nd) << 16)) |
                    ((unsigned long long)((unsigned)f2bf(acc.z * nd) | ((unsigned)f2bf(acc.w * nd) << 16)) << 32);
                // 8B LDS write; 32 lanes -> contiguous 256B row segment (conflict-free)
                *(unsigned long long*)&Ag[(size_t)(wv * 16 + i) * KP + l5 * 4] = p;
            }
        }
    }
    // No barrier: this wave reads back only the Ag rows it wrote (lgkmcnt ordering).

    // ---------- phase 2: GEMM 16 rows x 128 cols ----------
    f32x4 acc[8];
#pragma unroll
    for (int ct = 0; ct < 8; ++ct) acc[ct] = (f32x4){0.f, 0.f, 0.f, 0.f};

    for (int ks = 0; ks < 4; ++ks) {
        int kb = ks * 32 + quad * 8;
        bf16x8 ah = *(const bf16x8*)&Ag[(wv * 16 + l15) * KP + kb];
#pragma unroll
        for (int ct = 0; ct < 8; ++ct) {
            const short* bp = Wl + (ct * 16 + l15) * KP + kb;
            bf16x8 bh = *(const bf16x8*)bp;
            bf16x8 bl = *(const bf16x8*)(Wtl + ((ks * 8 + ct) * 16 + l15) * 32 + quad * 8);
            acc[ct] = __builtin_amdgcn_mfma_f32_16x16x32_bf16(ah, bh, acc[ct], 0, 0, 0);
            acc[ct] = __builtin_amdgcn_mfma_f32_16x16x32_bf16(ah, bl, acc[ct], 0, 0, 0);
        }
    }

    // ---------- epilogue: relu + residual + optional Hs pack (round-7 proven pattern) ----------
    bool doHs = (HsOut != nullptr);
    int rbase = row0 + wv * 16 + quad * 4;
    float ns[4];
    if (doHs) {
#pragma unroll
        for (int rj = 0; rj < 4; ++rj) {
            int row = rbase + rj;
            ns[rj] = (row < N) ? norm_s[row] : 0.f;
        }
    }
#pragma unroll
    for (int ct = 0; ct < 8; ++ct) {
        int col = ct * 16 + l15;
        float bv = bias_s[col];
#pragma unroll
        for (int rj = 0; rj < 4; ++rj) {
            int row = rbase + rj;
            if (row < N) {
                float o = fmaxf(acc[ct][rj] + bv, 0.f) + Hres[(size_t)row * DIMN + col];
                __builtin_nontemporal_store(o, &tgt[(size_t)row * DIMN + col]);
                if (doHs) HsOut[(size_t)row * DIMN + col] = f2bf(o * ns[rj]);
            }
        }
    }
}

static inline char* align256(char* p) {
    return (char*)(((uintptr_t)p + 255) & ~(uintptr_t)255);
}

extern "C" void kernel_launch(void* const* d_in, const int* in_sizes, int n_in,
                              void* d_out, int out_size, void* d_ws, size_t ws_size,
                              hipStream_t stream) {
    const float* h_in = (const float*)d_in[0];
    const int* src = (const int*)d_in[1];
    const int* dst = (const int*)d_in[2];
    const float* W_embed = (const float*)d_in[3];
    const float* b_embed = (const float*)d_in[4];
    const float* Ws = (const float*)d_in[5];
    const float* bs = (const float*)d_in[6];
    float* out = (float*)d_out;

    const int N = in_sizes[0] / DIMN;  // 100000
    const int E = in_sizes[1];         // 1600000
    const int W = (N + 1) / 2;         // packed degOut words
    const int NBUK = (N + BUCKW - 1) >> BQL;  // 196

    // -------- workspace carve --------
    char* w = (char*)d_ws;
    float* Hc = (float*)w;               w = align256(w + (size_t)N * DIMN * 4);
    unsigned short* HsA = (unsigned short*)w;  w = align256(w + (size_t)N * DIMN * 2);
    unsigned short* HsB = (unsigned short*)w;  w = align256(w + (size_t)N * DIMN * 2);
    int2* pairs = (int2*)w;              w = align256(w + (size_t)NBUK * BUCKCAP * 8);
    int* csr = (int*)w;                  w = align256(w + (size_t)NBUK * BUCKCAP * 4);
    int* rowptr = (int*)w;               w = align256(w + (size_t)N * 4);
    int* deg = (int*)w;                  w = align256(w + (size_t)N * 4);
    int* gcur = (int*)w;                 w = align256(w + (size_t)NBUK * 4);
    unsigned int* degOutP = (unsigned int*)w;  w = align256(w + (size_t)HP_C * W * 4);
    float* norm_s = (float*)w;           w = align256(w + (size_t)N * 4);
    float* norm_d = (float*)w;           w = align256(w + (size_t)N * 4);
    short* wt = (short*)w;               w = align256(w + (size_t)5 * WTSH * 2);
    short* wtl = (short*)w;              w = align256(w + (size_t)5 * WTL_SH * 2);

    (void)hipMemsetAsync(gcur, 0, (size_t)NBUK * 4, stream);

    int gb256 = (N + 255) / 256;         // 391 embed blocks (512 thr, 256 rows)
    int gb128 = (N + 127) / 128;         // 782 fused layer blocks (512 thr, 128 rows)
    int nb = (W + 255) / 256;
    int bb = (E + BSCH - 1) / BSCH;      // 391

    // degOut histogram partials (no atomic flush) + weight prep, role-split
    k_pre<<<HIST_BLOCKS + 5, 256, 0, stream>>>(src, W_embed, Ws, degOutP, wt, wtl, N, E);

    // binned counting-sort CSR
    k_binsort<<<bb, 256, 0, stream>>>(src, dst, gcur, pairs, E, NBUK);
    k_build<<<NBUK, 256, 0, stream>>>(pairs, gcur, csr, rowptr, deg, N);

    // norms (deg from build; degOut from histogram partials)
    k_norms<<<nb, 256, 0, stream>>>(deg, degOutP, norm_d, norm_s, N);

    // embed GEMM with fused Hs=bf16(Hc*norm_s) epilogue -> HsA
    k_gemm_f32<<<gb256, 512, 0, stream>>>(h_in, wt, b_embed, Hc, norm_s, HsA, N);

    // fused layers: aggregate(HsIn) + GEMM + epilogue (writes HsOut = other buffer)
    unsigned short* hs_in = HsA;
    unsigned short* hs_out = HsB;
    for (int l = 0; l < NLAYERS; ++l) {
        float* tgt = (l == NLAYERS - 1) ? out : Hc;
        unsigned short* ho = (l == NLAYERS - 1) ? (unsigned short*)nullptr : hs_out;
        k_layer<<<gb128, 512, 0, stream>>>((const unsigned int*)hs_in, csr, rowptr, deg,
                                           norm_d, wt + (size_t)(l + 1) * WTSH,
                                           wtl + (size_t)(l + 1) * WTL_SH,
                                           bs + (size_t)l * DIMN, Hc, tgt, norm_s, ho, N);
        unsigned short* t = hs_in; hs_in = hs_out; hs_out = t;
    }
}

// Round 10
// 613.260 us; speedup vs baseline: 1.3621x; 1.3621x over previous
//
#include <hip/hip_runtime.h>

#define DIMN 128
#define NLAYERS 4
#define KP 136                 // padded k-stride for transposed W
#define WTSH (2 * DIMN * KP)   // shorts per prepped matrix (hi plane + lo plane)

// ---- binned counting-sort CSR parameters ----
#define BQL 9                  // log2(bucket width in nodes)
#define BUCKW 512              // nodes per bucket
#define BUCKCAP 10240          // edge capacity per bucket (mean 8192, +22 sigma)
#define BSCH 4096              // edges per binsort block
#define NBUK_MAX 256           // static LDS sizing (runtime NBUK = 196)

// degOut histogram partitioning: P node-partitions x C edge-chunks, partial arrays
#define HP_P 3
#define HP_C 48
#define HIST_BLOCKS (HP_P * HP_C)   // 144
#define HW_WORDS 16667              // ceil(ceil(N/2)/HP_P) packed words; 66,668 B LDS

typedef __attribute__((ext_vector_type(8))) short bf16x8;  // 8 bf16 = 4 VGPRs
typedef __attribute__((ext_vector_type(4))) float f32x4;
typedef __attribute__((ext_vector_type(2))) unsigned long long u64x2;

__device__ inline float bfu2f(unsigned int u) { return __uint_as_float(u << 16); }
__device__ inline unsigned short f2bf(float f) {
    unsigned int u = __float_as_uint(f);
    return (unsigned short)((u + 0x7fffu + ((u >> 16) & 1u)) >> 16);  // RTNE
}
__device__ inline unsigned pack2(float a, float b) {
    return (unsigned)f2bf(a) | ((unsigned)f2bf(b) << 16);
}
__device__ inline float blo(unsigned int u) { return __uint_as_float(u << 16); }
__device__ inline float bhi(unsigned int u) { return __uint_as_float(u & 0xffff0000u); }

// ---------------- pre kernel: degOut histogram partials + W prep (role split) ----------------
__global__ __launch_bounds__(256) void k_pre(const int* __restrict__ src,
                                             const float* __restrict__ We,
                                             const float* __restrict__ Wlayers,
                                             unsigned int* __restrict__ degOutP,  // [HP_C][W]
                                             short* __restrict__ wt, int N, int E) {
    __shared__ unsigned int hsm[HW_WORDS];
    int tid = threadIdx.x;
    int bid = blockIdx.x;

    if (bid < HIST_BLOCKS) {
        int c = bid / HP_P;
        int p = bid % HP_P;
        int W = (N + 1) / 2;                   // packed words for all nodes
        int w0 = p * HW_WORDS;
        int wn = min(HW_WORDS, W - w0);
        if (wn <= 0) return;
        int per = ((E + HP_C - 1) / HP_C + 3) & ~3;  // chunk size, multiple of 4
        int e0 = c * per;
        int e1 = min(e0 + per, E);
        if (e0 >= e1) {  // still must zero-fill our exclusive output range
            for (int i = tid; i < wn; i += 256) degOutP[(size_t)c * W + w0 + i] = 0u;
            return;
        }
        for (int i = tid; i < wn; i += 256) hsm[i] = 0u;
        __syncthreads();
        int nvec = (e1 - e0) >> 2;
        const int4* sv = (const int4*)(src + e0);
        for (int it = tid; it < nvec; it += 256) {
            int4 v = sv[it];
            int w;
            w = (v.x >> 1) - w0; if ((unsigned)w < (unsigned)wn) atomicAdd(&hsm[w], 1u << ((v.x & 1) << 4));
            w = (v.y >> 1) - w0; if ((unsigned)w < (unsigned)wn) atomicAdd(&hsm[w], 1u << ((v.y & 1) << 4));
            w = (v.z >> 1) - w0; if ((unsigned)w < (unsigned)wn) atomicAdd(&hsm[w], 1u << ((v.z & 1) << 4));
            w = (v.w >> 1) - w0; if ((unsigned)w < (unsigned)wn) atomicAdd(&hsm[w], 1u << ((v.w & 1) << 4));
        }
        for (int j = e0 + (nvec << 2) + tid; j < e1; j += 256) {
            int s = src[j];
            int w = (s >> 1) - w0;
            if ((unsigned)w < (unsigned)wn) atomicAdd(&hsm[w], 1u << ((s & 1) << 4));
        }
        __syncthreads();
        // exclusive flush: plain coalesced stores, no atomics
        for (int i = tid; i < wn; i += 256) degOutP[(size_t)c * W + w0 + i] = hsm[i];
        return;
    }

    // ---------------- wprep role: split/transpose the 5 weight matrices ----------------
    {
        int m = bid - HIST_BLOCKS;  // 0 = embed, 1..4 = layers
        const float* Wm = (m == 0) ? We : Wlayers + (size_t)(m - 1) * DIMN * DIMN;
        short* o = wt + (size_t)m * WTSH;
#pragma unroll
        for (int it = 0; it < 16; ++it) {
            int f = it * 1024 + tid * 4;
            float4 v = *(const float4*)(Wm + f);
            int k = f >> 7, n = f & 127;
            float vv[4] = {v.x, v.y, v.z, v.w};
#pragma unroll
            for (int j = 0; j < 4; ++j) {
                unsigned short hb = f2bf(vv[j]);
                float lo = vv[j] - bfu2f(hb);
                o[(n + j) * KP + k] = (short)hb;
                o[DIMN * KP + (n + j) * KP + k] = (short)f2bf(lo);
            }
        }
    }
}

// ------- binsort: LDS counting-sort edges into 512-node dst buckets, coalesced flush -------
__global__ __launch_bounds__(256) void k_binsort(const int* __restrict__ src,
                                                 const int* __restrict__ dst,
                                                 int* __restrict__ gcur,
                                                 int2* __restrict__ pairs,
                                                 int E, int NBUK) {
    __shared__ int cnt[NBUK_MAX];
    __shared__ int bofs[NBUK_MAX];
    __shared__ int gof[NBUK_MAX];
    __shared__ int scan_s[256];
    __shared__ int2 stg[BSCH];       // 32 KB
    int tid = threadIdx.x;
    int e0 = blockIdx.x * BSCH;
    int n = min(BSCH, E - e0);
    if (n <= 0) return;
    cnt[tid] = 0;
    __syncthreads();

    int nv = n >> 2;
    const int4* dv4 = (const int4*)(dst + e0);
    for (int it = tid; it < nv; it += 256) {
        int4 d = dv4[it];
        atomicAdd(&cnt[d.x >> BQL], 1);
        atomicAdd(&cnt[d.y >> BQL], 1);
        atomicAdd(&cnt[d.z >> BQL], 1);
        atomicAdd(&cnt[d.w >> BQL], 1);
    }
    for (int j = (nv << 2) + tid; j < n; j += 256) {
        atomicAdd(&cnt[dst[e0 + j] >> BQL], 1);
    }
    __syncthreads();

    // inclusive Hillis-Steele scan over 256 (NBUK <= 256)
    int myc = cnt[tid];
    scan_s[tid] = myc;
    __syncthreads();
    for (int off = 1; off < 256; off <<= 1) {
        int x = scan_s[tid];
        if (tid >= off) x += scan_s[tid - off];
        __syncthreads();
        scan_s[tid] = x;
        __syncthreads();
    }
    bofs[tid] = scan_s[tid] - myc;        // exclusive local prefix
    gof[tid] = (myc > 0 && tid < NBUK) ? atomicAdd(&gcur[tid], myc) : 0;
    cnt[tid] = 0;                          // reuse as local cursor
    __syncthreads();

    // stage pass: place edges bucket-sorted in LDS
    const int4* sv4 = (const int4*)(src + e0);
    for (int it = tid; it < nv; it += 256) {
        int4 d = dv4[it];
        int4 s = sv4[it];
        int b, p;
        b = d.x >> BQL; p = bofs[b] + atomicAdd(&cnt[b], 1); stg[p] = make_int2(s.x, d.x);
        b = d.y >> BQL; p = bofs[b] + atomicAdd(&cnt[b], 1); stg[p] = make_int2(s.y, d.y);
        b = d.z >> BQL; p = bofs[b] + atomicAdd(&cnt[b], 1); stg[p] = make_int2(s.z, d.z);
        b = d.w >> BQL; p = bofs[b] + atomicAdd(&cnt[b], 1); stg[p] = make_int2(s.w, d.w);
    }
    for (int j = (nv << 2) + tid; j < n; j += 256) {
        int d = dst[e0 + j], s = src[e0 + j];
        int b = d >> BQL;
        int p = bofs[b] + atomicAdd(&cnt[b], 1);
        stg[p] = make_int2(s, d);
    }
    __syncthreads();

    // flush: consecutive i within a bucket -> consecutive global positions (coalesced runs)
    for (int i = tid; i < n; i += 256) {
        int2 pr = stg[i];
        int b = pr.y >> BQL;
        int go = gof[b] + (i - bofs[b]);
        if (go < BUCKCAP) pairs[(size_t)b * BUCKCAP + go] = pr;
    }
}

// ------- build: per-bucket local counting sort -> csr (sorted src), rowptr, deg -------
__global__ __launch_bounds__(256) void k_build(const int2* __restrict__ pairs,
                                               const int* __restrict__ gcur,
                                               int* __restrict__ csr,
                                               int* __restrict__ rowptr,
                                               int* __restrict__ deg, int N) {
    int b = blockIdx.x;
    int tid = threadIdx.x;
    int cntb = gcur[b];
    if (cntb > BUCKCAP) cntb = BUCKCAP;
    __shared__ int c[BUCKW];
    __shared__ int pf[BUCKW];
    c[tid] = 0; c[tid + 256] = 0;
    __syncthreads();
    const int2* bp = pairs + (size_t)b * BUCKCAP;
    for (int i = tid; i < cntb; i += 256) atomicAdd(&c[bp[i].y & (BUCKW - 1)], 1);
    __syncthreads();
    pf[tid] = c[tid]; pf[tid + 256] = c[tid + 256];
    __syncthreads();
    // inclusive scan over 512 with 256 threads (double-sync Hillis-Steele)
    for (int off = 1; off < BUCKW; off <<= 1) {
        int i0 = tid, i1 = tid + 256;
        int v0 = pf[i0] + ((i0 >= off) ? pf[i0 - off] : 0);
        int v1 = pf[i1] + ((i1 >= off) ? pf[i1 - off] : 0);
        __syncthreads();
        pf[i0] = v0; pf[i1] = v1;
        __syncthreads();
    }
    {   // exclusive prefix in pf; emit rowptr/deg; reset c as cursor
        int i0 = tid, i1 = tid + 256;
        int c0 = c[i0], c1 = c[i1];
        int ex0 = pf[i0] - c0, ex1 = pf[i1] - c1;
        pf[i0] = ex0; pf[i1] = ex1;
        int gn0 = (b << BQL) + i0, gn1 = (b << BQL) + i1;
        if (gn0 < N) { rowptr[gn0] = b * BUCKCAP + ex0; deg[gn0] = c0; }
        if (gn1 < N) { rowptr[gn1] = b * BUCKCAP + ex1; deg[gn1] = c1; }
        c[i0] = 0; c[i1] = 0;
    }
    __syncthreads();
    int* cb = csr + (size_t)b * BUCKCAP;
    for (int i = tid; i < cntb; i += 256) {
        int2 p = bp[i];
        int ld = p.y & (BUCKW - 1);
        int pos = pf[ld] + atomicAdd(&c[ld], 1);
        cb[pos] = p.x;   // random 4B within ~40KB L2-resident window
    }
}

// ---------------- norms: deg (in) direct; degOut = sum of histogram partials ----------------
__global__ __launch_bounds__(256) void k_norms(const int* __restrict__ deg,
                                               const unsigned int* __restrict__ degOutP,
                                               float* __restrict__ norm_d,
                                               float* __restrict__ norm_s, int N) {
    int i = blockIdx.x * 256 + threadIdx.x;  // one packed word = 2 nodes per thread
    int W = (N + 1) / 2;
    if (i < W) {
        unsigned s0 = 0, s1 = 0;
#pragma unroll 8
        for (int c = 0; c < HP_C; ++c) {
            unsigned v = degOutP[(size_t)c * W + i];
            s0 += v & 0xffffu;
            s1 += v >> 16;
        }
        int n0 = 2 * i, n1 = 2 * i + 1;
        norm_s[n0] = rsqrtf(fmaxf((float)s0, 1.0f));
        norm_d[n0] = rsqrtf(fmaxf((float)deg[n0], 1.0f));
        if (n1 < N) {
            norm_s[n1] = rsqrtf(fmaxf((float)s1, 1.0f));
            norm_d[n1] = rsqrtf(fmaxf((float)deg[n1], 1.0f));
        }
    }
}

// ---- MFMA GEMM (embed): f32 A, 3-term bf16 split; full W in LDS; 512-thread/8-wave blocks ----
// (round-7 proven, untouched)
__global__ __launch_bounds__(512) void k_gemm_f32(const float* __restrict__ A,
                                                  const short* __restrict__ Wt,
                                                  const float* __restrict__ bg,
                                                  float* __restrict__ tgt,
                                                  const float* __restrict__ norm_s,
                                                  unsigned short* __restrict__ Hs, int N) {
    __shared__ short Wl[WTSH];        // 69,632 B
    __shared__ float bias_s[DIMN];
    int tid = threadIdx.x;
    {
        const uint4* g = (const uint4*)Wt;
        uint4* l = (uint4*)Wl;
#pragma unroll
        for (int it = 0; it < 9; ++it) {
            int ix = it * 512 + tid;
            if (ix < WTSH / 8) l[ix] = g[ix];
        }
        if (tid < DIMN) bias_s[tid] = bg[tid];
    }
    __syncthreads();

    int lane = tid & 63;
    int wv = tid >> 6;                 // 0..7
    int quad = lane >> 4;
    int l15 = lane & 15;
    int row0 = blockIdx.x * 256 + wv * 32;

    f32x4 acc[2][8];
#pragma unroll
    for (int s = 0; s < 2; ++s)
#pragma unroll
        for (int ct = 0; ct < 8; ++ct) acc[s][ct] = (f32x4){0.f, 0.f, 0.f, 0.f};

    for (int ks = 0; ks < 4; ++ks) {
        int kb = ks * 32 + quad * 8;
        bf16x8 ah[2], al[2];
#pragma unroll
        for (int s = 0; s < 2; ++s) {
            int r = row0 + s * 16 + l15;
            if (r > N - 1) r = N - 1;
            const float* ap = A + (size_t)r * DIMN + kb;
            float4 p = *(const float4*)ap;
            float4 q = *(const float4*)(ap + 4);
            float fv[8] = {p.x, p.y, p.z, p.w, q.x, q.y, q.z, q.w};
#pragma unroll
            for (int j = 0; j < 8; ++j) {
                unsigned short hb = f2bf(fv[j]);
                ah[s][j] = (short)hb;
                al[s][j] = (short)f2bf(fv[j] - bfu2f(hb));
            }
        }
#pragma unroll
        for (int ct = 0; ct < 8; ++ct) {
            const short* bp = Wl + (ct * 16 + l15) * KP + kb;
            bf16x8 bh = *(const bf16x8*)bp;
            bf16x8 bl = *(const bf16x8*)(bp + DIMN * KP);
#pragma unroll
            for (int s = 0; s < 2; ++s) {
                acc[s][ct] = __builtin_amdgcn_mfma_f32_16x16x32_bf16(ah[s], bh, acc[s][ct], 0, 0, 0);
                acc[s][ct] = __builtin_amdgcn_mfma_f32_16x16x32_bf16(al[s], bh, acc[s][ct], 0, 0, 0);
                acc[s][ct] = __builtin_amdgcn_mfma_f32_16x16x32_bf16(ah[s], bl, acc[s][ct], 0, 0, 0);
            }
        }
    }

#pragma unroll
    for (int s = 0; s < 2; ++s) {
        int rbase = row0 + s * 16 + quad * 4;
        float ns[4];
#pragma unroll
        for (int rj = 0; rj < 4; ++rj) {
            int row = rbase + rj;
            ns[rj] = (row < N) ? norm_s[row] : 0.f;
        }
#pragma unroll
        for (int ct = 0; ct < 8; ++ct) {
            int col = ct * 16 + l15;
            float bv = bias_s[col];
#pragma unroll
            for (int rj = 0; rj < 4; ++rj) {
                int row = rbase + rj;
                if (row < N) {
                    float o = acc[s][ct][rj] + bv;
                    __builtin_nontemporal_store(o, &tgt[(size_t)row * DIMN + col]);
                    Hs[(size_t)row * DIMN + col] = f2bf(o * ns[rj]);
                }
            }
        }
    }
}

// ---- MFMA GEMM (layer): bf16 A; full W in LDS; relu+residual epilogue; 512-thread/8-wave ----
// (round-7 proven, untouched)
__global__ __launch_bounds__(512) void k_gemm_bf(const unsigned short* __restrict__ A,
                                                 const short* __restrict__ Wt,
                                                 const float* __restrict__ bg,
                                                 const float* __restrict__ Hres,
                                                 float* __restrict__ tgt,
                                                 const float* __restrict__ norm_s,
                                                 unsigned short* __restrict__ Hs, int N) {
    __shared__ short Wl[WTSH];        // 69,632 B
    __shared__ float bias_s[DIMN];
    int tid = threadIdx.x;
    {
        const uint4* g = (const uint4*)Wt;
        uint4* l = (uint4*)Wl;
#pragma unroll
        for (int it = 0; it < 9; ++it) {
            int ix = it * 512 + tid;
            if (ix < WTSH / 8) l[ix] = g[ix];
        }
        if (tid < DIMN) bias_s[tid] = bg[tid];
    }
    __syncthreads();

    int lane = tid & 63;
    int wv = tid >> 6;                 // 0..7
    int quad = lane >> 4;
    int l15 = lane & 15;
    int row0 = blockIdx.x * 256 + wv * 32;

    f32x4 acc[2][8];
#pragma unroll
    for (int s = 0; s < 2; ++s)
#pragma unroll
        for (int ct = 0; ct < 8; ++ct) acc[s][ct] = (f32x4){0.f, 0.f, 0.f, 0.f};

    for (int ks = 0; ks < 4; ++ks) {
        int kb = ks * 32 + quad * 8;
        bf16x8 ah[2];
#pragma unroll
        for (int s = 0; s < 2; ++s) {
            int r = row0 + s * 16 + l15;
            if (r > N - 1) r = N - 1;
            ah[s] = *(const bf16x8*)(A + (size_t)r * DIMN + kb);  // 16 B aligned
        }
#pragma unroll
        for (int ct = 0; ct < 8; ++ct) {
            const short* bp = Wl + (ct * 16 + l15) * KP + kb;
            bf16x8 bh = *(const bf16x8*)bp;
            bf16x8 bl = *(const bf16x8*)(bp + DIMN * KP);
#pragma unroll
            for (int s = 0; s < 2; ++s) {
                acc[s][ct] = __builtin_amdgcn_mfma_f32_16x16x32_bf16(ah[s], bh, acc[s][ct], 0, 0, 0);
                acc[s][ct] = __builtin_amdgcn_mfma_f32_16x16x32_bf16(ah[s], bl, acc[s][ct], 0, 0, 0);
            }
        }
    }

    bool doHs = (Hs != nullptr);
#pragma unroll
    for (int s = 0; s < 2; ++s) {
        int rbase = row0 + s * 16 + quad * 4;
        float ns[4];
        if (doHs) {
#pragma unroll
            for (int rj = 0; rj < 4; ++rj) {
                int row = rbase + rj;
                ns[rj] = (row < N) ? norm_s[row] : 0.f;
            }
        }
#pragma unroll
        for (int ct = 0; ct < 8; ++ct) {
            int col = ct * 16 + l15;
            float bv = bias_s[col];
#pragma unroll
            for (int rj = 0; rj < 4; ++rj) {
                int row = rbase + rj;
                if (row < N) {
                    float o = fmaxf(acc[s][ct][rj] + bv, 0.f) + Hres[(size_t)row * DIMN + col];
                    __builtin_nontemporal_store(o, &tgt[(size_t)row * DIMN + col]);
                    if (doHs) Hs[(size_t)row * DIMN + col] = f2bf(o * ns[rj]);
                }
            }
        }
    }
}

// ------- SpMM v2: uint4 gathers, 4 edges/wave concurrent, 64B/lane in flight -------
// One wave per dst node. 16 lanes x 16B cover the 256B Hs row; 4 lane-groups = 4 edges
// in parallel; 16-edge main loop keeps 4x16B loads in flight per lane (2x round-7 MLP).
__global__ __launch_bounds__(256) void k_spmm(const uint4* __restrict__ Hs4,
                                              u64x2* __restrict__ AggB2,
                                              const int* __restrict__ csr,
                                              const int* __restrict__ rowptr,
                                              const int* __restrict__ deg,
                                              const float* __restrict__ norm_d, int N) {
    int wave = (blockIdx.x * blockDim.x + threadIdx.x) >> 6;
    int lane = threadIdx.x & 63;
    if (wave >= N) return;
    int cnt = deg[wave];
    const int* base = csr + rowptr[wave];
    int g = lane >> 4;    // edge slot 0..3
    int l4 = lane & 15;   // 16B chunk of row
    float acc[8];
#pragma unroll
    for (int j = 0; j < 8; ++j) acc[j] = 0.f;

#define ACC8(h)                                   \
    acc[0] += blo((h).x); acc[1] += bhi((h).x);   \
    acc[2] += blo((h).y); acc[3] += bhi((h).y);   \
    acc[4] += blo((h).z); acc[5] += bhi((h).z);   \
    acc[6] += blo((h).w); acc[7] += bhi((h).w);

    int e = 0;
    for (; e + 16 <= cnt; e += 16) {   // 4 x 16B in flight per lane
        int s0 = base[e + g];
        int s1 = base[e + 4 + g];
        int s2 = base[e + 8 + g];
        int s3 = base[e + 12 + g];
        uint4 h0 = Hs4[(size_t)s0 * 16 + l4];
        uint4 h1 = Hs4[(size_t)s1 * 16 + l4];
        uint4 h2 = Hs4[(size_t)s2 * 16 + l4];
        uint4 h3 = Hs4[(size_t)s3 * 16 + l4];
        ACC8(h0) ACC8(h1) ACC8(h2) ACC8(h3)
    }
    for (; e + 8 <= cnt; e += 8) {
        int s0 = base[e + g];
        int s1 = base[e + 4 + g];
        uint4 h0 = Hs4[(size_t)s0 * 16 + l4];
        uint4 h1 = Hs4[(size_t)s1 * 16 + l4];
        ACC8(h0) ACC8(h1)
    }
    for (; e < cnt; e += 4) {          // predicated tail, 4 edges/iter
        int ee = e + g;
        int sc = base[min(ee, cnt - 1)];
        uint4 hv = Hs4[(size_t)sc * 16 + l4];
        if (ee < cnt) { ACC8(hv) }
    }
#undef ACC8

    // reduce across the 4 edge-slot groups (lanes with equal l4)
#pragma unroll
    for (int j = 0; j < 8; ++j) {
        acc[j] += __shfl_xor(acc[j], 16);
        acc[j] += __shfl_xor(acc[j], 32);
    }
    if (g == 0) {
        float nd = norm_d[wave];
        unsigned u0 = pack2(acc[0] * nd, acc[1] * nd);
        unsigned u1 = pack2(acc[2] * nd, acc[3] * nd);
        unsigned u2 = pack2(acc[4] * nd, acc[5] * nd);
        unsigned u3 = pack2(acc[6] * nd, acc[7] * nd);
        u64x2 o;
        o[0] = (unsigned long long)u0 | ((unsigned long long)u1 << 32);
        o[1] = (unsigned long long)u2 | ((unsigned long long)u3 << 32);
        __builtin_nontemporal_store(o, &AggB2[(size_t)wave * 16 + l4]);
    }
}

static inline char* align256(char* p) {
    return (char*)(((uintptr_t)p + 255) & ~(uintptr_t)255);
}

extern "C" void kernel_launch(void* const* d_in, const int* in_sizes, int n_in,
                              void* d_out, int out_size, void* d_ws, size_t ws_size,
                              hipStream_t stream) {
    const float* h_in = (const float*)d_in[0];
    const int* src = (const int*)d_in[1];
    const int* dst = (const int*)d_in[2];
    const float* W_embed = (const float*)d_in[3];
    const float* b_embed = (const float*)d_in[4];
    const float* Ws = (const float*)d_in[5];
    const float* bs = (const float*)d_in[6];
    float* out = (float*)d_out;

    const int N = in_sizes[0] / DIMN;  // 100000
    const int E = in_sizes[1];         // 1600000
    const int W = (N + 1) / 2;         // packed degOut words
    const int NBUK = (N + BUCKW - 1) >> BQL;  // 196

    // -------- workspace carve --------
    char* w = (char*)d_ws;
    float* Hc = (float*)w;               w = align256(w + (size_t)N * DIMN * 4);
    unsigned short* AggB = (unsigned short*)w; w = align256(w + (size_t)N * DIMN * 2);
    unsigned short* Hs = (unsigned short*)w;   w = align256(w + (size_t)N * DIMN * 2);
    int2* pairs = (int2*)w;              w = align256(w + (size_t)NBUK * BUCKCAP * 8);
    int* csr = (int*)w;                  w = align256(w + (size_t)NBUK * BUCKCAP * 4);
    int* rowptr = (int*)w;               w = align256(w + (size_t)N * 4);
    int* deg = (int*)w;                  w = align256(w + (size_t)N * 4);
    int* gcur = (int*)w;                 w = align256(w + (size_t)NBUK * 4);
    unsigned int* degOutP = (unsigned int*)w;  w = align256(w + (size_t)HP_C * W * 4);
    float* norm_s = (float*)w;           w = align256(w + (size_t)N * 4);
    float* norm_d = (float*)w;           w = align256(w + (size_t)N * 4);
    short* wt = (short*)w;               w = align256(w + (size_t)5 * WTSH * 2);

    (void)hipMemsetAsync(gcur, 0, (size_t)NBUK * 4, stream);

    int gb = (N + 255) / 256;            // 391 (512-thread GEMM blocks, 256 rows each)
    int nb = (W + 255) / 256;
    int bb = (E + BSCH - 1) / BSCH;      // 391

    // degOut histogram partials (no atomic flush) + weight prep, role-split
    k_pre<<<HIST_BLOCKS + 5, 256, 0, stream>>>(src, W_embed, Ws, degOutP, wt, N, E);

    // binned counting-sort CSR
    k_binsort<<<bb, 256, 0, stream>>>(src, dst, gcur, pairs, E, NBUK);
    k_build<<<NBUK, 256, 0, stream>>>(pairs, gcur, csr, rowptr, deg, N);

    // norms (deg from build; degOut from histogram partials)
    k_norms<<<nb, 256, 0, stream>>>(deg, degOutP, norm_d, norm_s, N);

    // embed GEMM with fused Hs=bf16(Hc*norm_s) epilogue
    k_gemm_f32<<<gb, 512, 0, stream>>>(h_in, wt, b_embed, Hc, norm_s, Hs, N);

    // layers
    int sb = (N + 3) / 4;
    for (int l = 0; l < NLAYERS; ++l) {
        k_spmm<<<sb, 256, 0, stream>>>((const uint4*)Hs, (u64x2*)AggB, csr, rowptr, deg, norm_d, N);
        float* tgt = (l == NLAYERS - 1) ? out : Hc;
        unsigned short* hs_next = (l == NLAYERS - 1) ? (unsigned short*)nullptr : Hs;
        k_gemm_bf<<<gb, 512, 0, stream>>>(AggB, wt + (size_t)(l + 1) * WTSH,
                                          bs + (size_t)l * DIMN, Hc, tgt, norm_s, hs_next, N);
    }
}

// Round 11
// 582.234 us; speedup vs baseline: 1.4347x; 1.0533x over previous
//
#include <hip/hip_runtime.h>

#define DIMN 128
#define NLAYERS 4
#define KP 136                 // padded k-stride for transposed W
#define WTSH (2 * DIMN * KP)   // shorts per prepped matrix (hi plane + lo plane)

// ---- binned counting-sort CSR parameters ----
#define BQL 9                  // log2(bucket width in nodes)
#define BUCKW 512              // nodes per bucket
#define BUCKCAP 10240          // edge capacity per bucket (mean 8192, +22 sigma)
#define BSCH 4096              // edges per binsort block
#define NBUK_MAX 256           // static LDS sizing (runtime NBUK = 196)

// degOut histogram partitioning: P node-partitions x C edge-chunks, partial arrays
#define HP_P 3
#define HP_C 48
#define HIST_BLOCKS (HP_P * HP_C)   // 144
#define HW_WORDS 16667              // ceil(ceil(N/2)/HP_P) packed words; 66,668 B LDS

typedef __attribute__((ext_vector_type(8))) short bf16x8;  // 8 bf16 = 4 VGPRs
typedef __attribute__((ext_vector_type(4))) float f32x4;
typedef __attribute__((ext_vector_type(2))) unsigned long long u64x2;

__device__ inline float bfu2f(unsigned int u) { return __uint_as_float(u << 16); }
__device__ inline unsigned short f2bf(float f) {
    unsigned int u = __float_as_uint(f);
    return (unsigned short)((u + 0x7fffu + ((u >> 16) & 1u)) >> 16);  // RTNE
}
__device__ inline unsigned pack2(float a, float b) {
    return (unsigned)f2bf(a) | ((unsigned)f2bf(b) << 16);
}
__device__ inline float blo(unsigned int u) { return __uint_as_float(u << 16); }
__device__ inline float bhi(unsigned int u) { return __uint_as_float(u & 0xffff0000u); }

// ---------------- pre kernel: degOut histogram partials + W prep (role split) ----------------
__global__ __launch_bounds__(256) void k_pre(const int* __restrict__ src,
                                             const float* __restrict__ We,
                                             const float* __restrict__ Wlayers,
                                             unsigned int* __restrict__ degOutP,  // [HP_C][W]
                                             short* __restrict__ wt, int N, int E) {
    __shared__ unsigned int hsm[HW_WORDS];
    int tid = threadIdx.x;
    int bid = blockIdx.x;

    if (bid < HIST_BLOCKS) {
        int c = bid / HP_P;
        int p = bid % HP_P;
        int W = (N + 1) / 2;                   // packed words for all nodes
        int w0 = p * HW_WORDS;
        int wn = min(HW_WORDS, W - w0);
        if (wn <= 0) return;
        int per = ((E + HP_C - 1) / HP_C + 3) & ~3;  // chunk size, multiple of 4
        int e0 = c * per;
        int e1 = min(e0 + per, E);
        if (e0 >= e1) {  // still must zero-fill our exclusive output range
            for (int i = tid; i < wn; i += 256) degOutP[(size_t)c * W + w0 + i] = 0u;
            return;
        }
        for (int i = tid; i < wn; i += 256) hsm[i] = 0u;
        __syncthreads();
        int nvec = (e1 - e0) >> 2;
        const int4* sv = (const int4*)(src + e0);
        for (int it = tid; it < nvec; it += 256) {
            int4 v = sv[it];
            int w;
            w = (v.x >> 1) - w0; if ((unsigned)w < (unsigned)wn) atomicAdd(&hsm[w], 1u << ((v.x & 1) << 4));
            w = (v.y >> 1) - w0; if ((unsigned)w < (unsigned)wn) atomicAdd(&hsm[w], 1u << ((v.y & 1) << 4));
            w = (v.z >> 1) - w0; if ((unsigned)w < (unsigned)wn) atomicAdd(&hsm[w], 1u << ((v.z & 1) << 4));
            w = (v.w >> 1) - w0; if ((unsigned)w < (unsigned)wn) atomicAdd(&hsm[w], 1u << ((v.w & 1) << 4));
        }
        for (int j = e0 + (nvec << 2) + tid; j < e1; j += 256) {
            int s = src[j];
            int w = (s >> 1) - w0;
            if ((unsigned)w < (unsigned)wn) atomicAdd(&hsm[w], 1u << ((s & 1) << 4));
        }
        __syncthreads();
        // exclusive flush: plain coalesced stores, no atomics
        for (int i = tid; i < wn; i += 256) degOutP[(size_t)c * W + w0 + i] = hsm[i];
        return;
    }

    // ---------------- wprep role: split/transpose the 5 weight matrices ----------------
    {
        int m = bid - HIST_BLOCKS;  // 0 = embed, 1..4 = layers
        const float* Wm = (m == 0) ? We : Wlayers + (size_t)(m - 1) * DIMN * DIMN;
        short* o = wt + (size_t)m * WTSH;
#pragma unroll
        for (int it = 0; it < 16; ++it) {
            int f = it * 1024 + tid * 4;
            float4 v = *(const float4*)(Wm + f);
            int k = f >> 7, n = f & 127;
            float vv[4] = {v.x, v.y, v.z, v.w};
#pragma unroll
            for (int j = 0; j < 4; ++j) {
                unsigned short hb = f2bf(vv[j]);
                float lo = vv[j] - bfu2f(hb);
                o[(n + j) * KP + k] = (short)hb;
                o[DIMN * KP + (n + j) * KP + k] = (short)f2bf(lo);
            }
        }
    }
}

// ------- binsort: LDS counting-sort edges into 512-node dst buckets, coalesced flush -------
__global__ __launch_bounds__(256) void k_binsort(const int* __restrict__ src,
                                                 const int* __restrict__ dst,
                                                 int* __restrict__ gcur,
                                                 int2* __restrict__ pairs,
                                                 int E, int NBUK) {
    __shared__ int cnt[NBUK_MAX];
    __shared__ int bofs[NBUK_MAX];
    __shared__ int gof[NBUK_MAX];
    __shared__ int scan_s[256];
    __shared__ int2 stg[BSCH];       // 32 KB
    int tid = threadIdx.x;
    int e0 = blockIdx.x * BSCH;
    int n = min(BSCH, E - e0);
    if (n <= 0) return;
    cnt[tid] = 0;
    __syncthreads();

    int nv = n >> 2;
    const int4* dv4 = (const int4*)(dst + e0);
    for (int it = tid; it < nv; it += 256) {
        int4 d = dv4[it];
        atomicAdd(&cnt[d.x >> BQL], 1);
        atomicAdd(&cnt[d.y >> BQL], 1);
        atomicAdd(&cnt[d.z >> BQL], 1);
        atomicAdd(&cnt[d.w >> BQL], 1);
    }
    for (int j = (nv << 2) + tid; j < n; j += 256) {
        atomicAdd(&cnt[dst[e0 + j] >> BQL], 1);
    }
    __syncthreads();

    // inclusive Hillis-Steele scan over 256 (NBUK <= 256)
    int myc = cnt[tid];
    scan_s[tid] = myc;
    __syncthreads();
    for (int off = 1; off < 256; off <<= 1) {
        int x = scan_s[tid];
        if (tid >= off) x += scan_s[tid - off];
        __syncthreads();
        scan_s[tid] = x;
        __syncthreads();
    }
    bofs[tid] = scan_s[tid] - myc;        // exclusive local prefix
    gof[tid] = (myc > 0 && tid < NBUK) ? atomicAdd(&gcur[tid], myc) : 0;
    cnt[tid] = 0;                          // reuse as local cursor
    __syncthreads();

    // stage pass: place edges bucket-sorted in LDS
    const int4* sv4 = (const int4*)(src + e0);
    for (int it = tid; it < nv; it += 256) {
        int4 d = dv4[it];
        int4 s = sv4[it];
        int b, p;
        b = d.x >> BQL; p = bofs[b] + atomicAdd(&cnt[b], 1); stg[p] = make_int2(s.x, d.x);
        b = d.y >> BQL; p = bofs[b] + atomicAdd(&cnt[b], 1); stg[p] = make_int2(s.y, d.y);
        b = d.z >> BQL; p = bofs[b] + atomicAdd(&cnt[b], 1); stg[p] = make_int2(s.z, d.z);
        b = d.w >> BQL; p = bofs[b] + atomicAdd(&cnt[b], 1); stg[p] = make_int2(s.w, d.w);
    }
    for (int j = (nv << 2) + tid; j < n; j += 256) {
        int d = dst[e0 + j], s = src[e0 + j];
        int b = d >> BQL;
        int p = bofs[b] + atomicAdd(&cnt[b], 1);
        stg[p] = make_int2(s, d);
    }
    __syncthreads();

    // flush: consecutive i within a bucket -> consecutive global positions (coalesced runs)
    for (int i = tid; i < n; i += 256) {
        int2 pr = stg[i];
        int b = pr.y >> BQL;
        int go = gof[b] + (i - bofs[b]);
        if (go < BUCKCAP) pairs[(size_t)b * BUCKCAP + go] = pr;
    }
}

// ------- build: per-bucket local counting sort -> csr (sorted src), rowptr, deg -------
__global__ __launch_bounds__(256) void k_build(const int2* __restrict__ pairs,
                                               const int* __restrict__ gcur,
                                               int* __restrict__ csr,
                                               int* __restrict__ rowptr,
                                               int* __restrict__ deg, int N) {
    int b = blockIdx.x;
    int tid = threadIdx.x;
    int cntb = gcur[b];
    if (cntb > BUCKCAP) cntb = BUCKCAP;
    __shared__ int c[BUCKW];
    __shared__ int pf[BUCKW];
    c[tid] = 0; c[tid + 256] = 0;
    __syncthreads();
    const int2* bp = pairs + (size_t)b * BUCKCAP;
    for (int i = tid; i < cntb; i += 256) atomicAdd(&c[bp[i].y & (BUCKW - 1)], 1);
    __syncthreads();
    pf[tid] = c[tid]; pf[tid + 256] = c[tid + 256];
    __syncthreads();
    // inclusive scan over 512 with 256 threads (double-sync Hillis-Steele)
    for (int off = 1; off < BUCKW; off <<= 1) {
        int i0 = tid, i1 = tid + 256;
        int v0 = pf[i0] + ((i0 >= off) ? pf[i0 - off] : 0);
        int v1 = pf[i1] + ((i1 >= off) ? pf[i1 - off] : 0);
        __syncthreads();
        pf[i0] = v0; pf[i1] = v1;
        __syncthreads();
    }
    {   // exclusive prefix in pf; emit rowptr/deg; reset c as cursor
        int i0 = tid, i1 = tid + 256;
        int c0 = c[i0], c1 = c[i1];
        int ex0 = pf[i0] - c0, ex1 = pf[i1] - c1;
        pf[i0] = ex0; pf[i1] = ex1;
        int gn0 = (b << BQL) + i0, gn1 = (b << BQL) + i1;
        if (gn0 < N) { rowptr[gn0] = b * BUCKCAP + ex0; deg[gn0] = c0; }
        if (gn1 < N) { rowptr[gn1] = b * BUCKCAP + ex1; deg[gn1] = c1; }
        c[i0] = 0; c[i1] = 0;
    }
    __syncthreads();
    int* cb = csr + (size_t)b * BUCKCAP;
    for (int i = tid; i < cntb; i += 256) {
        int2 p = bp[i];
        int ld = p.y & (BUCKW - 1);
        int pos = pf[ld] + atomicAdd(&c[ld], 1);
        cb[pos] = p.x;   // random 4B within ~40KB L2-resident window
    }
}

// ---------------- norms: deg (in) direct; degOut = sum of histogram partials ----------------
__global__ __launch_bounds__(256) void k_norms(const int* __restrict__ deg,
                                               const unsigned int* __restrict__ degOutP,
                                               float* __restrict__ norm_d,
                                               float* __restrict__ norm_s, int N) {
    int i = blockIdx.x * 256 + threadIdx.x;  // one packed word = 2 nodes per thread
    int W = (N + 1) / 2;
    if (i < W) {
        unsigned s0 = 0, s1 = 0;
#pragma unroll 8
        for (int c = 0; c < HP_C; ++c) {
            unsigned v = degOutP[(size_t)c * W + i];
            s0 += v & 0xffffu;
            s1 += v >> 16;
        }
        int n0 = 2 * i, n1 = 2 * i + 1;
        norm_s[n0] = rsqrtf(fmaxf((float)s0, 1.0f));
        norm_d[n0] = rsqrtf(fmaxf((float)deg[n0], 1.0f));
        if (n1 < N) {
            norm_s[n1] = rsqrtf(fmaxf((float)s1, 1.0f));
            norm_d[n1] = rsqrtf(fmaxf((float)deg[n1], 1.0f));
        }
    }
}

// ---- MFMA GEMM (embed): f32 A, 3-term bf16 split; full W in LDS; 512-thread/8-wave blocks ----
// (round-7 structure; tgt store now PLAIN so Hc stays cache-resident for layer reads)
__global__ __launch_bounds__(512) void k_gemm_f32(const float* __restrict__ A,
                                                  const short* __restrict__ Wt,
                                                  const float* __restrict__ bg,
                                                  float* __restrict__ tgt,
                                                  const float* __restrict__ norm_s,
                                                  unsigned short* __restrict__ Hs, int N) {
    __shared__ short Wl[WTSH];        // 69,632 B
    __shared__ float bias_s[DIMN];
    int tid = threadIdx.x;
    {
        const uint4* g = (const uint4*)Wt;
        uint4* l = (uint4*)Wl;
#pragma unroll
        for (int it = 0; it < 9; ++it) {
            int ix = it * 512 + tid;
            if (ix < WTSH / 8) l[ix] = g[ix];
        }
        if (tid < DIMN) bias_s[tid] = bg[tid];
    }
    __syncthreads();

    int lane = tid & 63;
    int wv = tid >> 6;                 // 0..7
    int quad = lane >> 4;
    int l15 = lane & 15;
    int row0 = blockIdx.x * 256 + wv * 32;

    f32x4 acc[2][8];
#pragma unroll
    for (int s = 0; s < 2; ++s)
#pragma unroll
        for (int ct = 0; ct < 8; ++ct) acc[s][ct] = (f32x4){0.f, 0.f, 0.f, 0.f};

    for (int ks = 0; ks < 4; ++ks) {
        int kb = ks * 32 + quad * 8;
        bf16x8 ah[2], al[2];
#pragma unroll
        for (int s = 0; s < 2; ++s) {
            int r = row0 + s * 16 + l15;
            if (r > N - 1) r = N - 1;
            const float* ap = A + (size_t)r * DIMN + kb;
            float4 p = *(const float4*)ap;
            float4 q = *(const float4*)(ap + 4);
            float fv[8] = {p.x, p.y, p.z, p.w, q.x, q.y, q.z, q.w};
#pragma unroll
            for (int j = 0; j < 8; ++j) {
                unsigned short hb = f2bf(fv[j]);
                ah[s][j] = (short)hb;
                al[s][j] = (short)f2bf(fv[j] - bfu2f(hb));
            }
        }
#pragma unroll
        for (int ct = 0; ct < 8; ++ct) {
            const short* bp = Wl + (ct * 16 + l15) * KP + kb;
            bf16x8 bh = *(const bf16x8*)bp;
            bf16x8 bl = *(const bf16x8*)(bp + DIMN * KP);
#pragma unroll
            for (int s = 0; s < 2; ++s) {
                acc[s][ct] = __builtin_amdgcn_mfma_f32_16x16x32_bf16(ah[s], bh, acc[s][ct], 0, 0, 0);
                acc[s][ct] = __builtin_amdgcn_mfma_f32_16x16x32_bf16(al[s], bh, acc[s][ct], 0, 0, 0);
                acc[s][ct] = __builtin_amdgcn_mfma_f32_16x16x32_bf16(ah[s], bl, acc[s][ct], 0, 0, 0);
            }
        }
    }

#pragma unroll
    for (int s = 0; s < 2; ++s) {
        int rbase = row0 + s * 16 + quad * 4;
        float ns[4];
#pragma unroll
        for (int rj = 0; rj < 4; ++rj) {
            int row = rbase + rj;
            ns[rj] = (row < N) ? norm_s[row] : 0.f;
        }
#pragma unroll
        for (int ct = 0; ct < 8; ++ct) {
            int col = ct * 16 + l15;
            float bv = bias_s[col];
#pragma unroll
            for (int rj = 0; rj < 4; ++rj) {
                int row = rbase + rj;
                if (row < N) {
                    float o = acc[s][ct][rj] + bv;
                    tgt[(size_t)row * DIMN + col] = o;   // plain: keep Hc in L2/L3
                    Hs[(size_t)row * DIMN + col] = f2bf(o * ns[rj]);
                }
            }
        }
    }
}

// ---- MFMA GEMM (layer): bf16 A; full W in LDS; relu+residual epilogue; 512-thread/8-wave ----
// (round-7 structure; tgt store now PLAIN so next layer's Hres read is cache-hit)
__global__ __launch_bounds__(512) void k_gemm_bf(const unsigned short* __restrict__ A,
                                                 const short* __restrict__ Wt,
                                                 const float* __restrict__ bg,
                                                 const float* __restrict__ Hres,
                                                 float* __restrict__ tgt,
                                                 const float* __restrict__ norm_s,
                                                 unsigned short* __restrict__ Hs, int N) {
    __shared__ short Wl[WTSH];        // 69,632 B
    __shared__ float bias_s[DIMN];
    int tid = threadIdx.x;
    {
        const uint4* g = (const uint4*)Wt;
        uint4* l = (uint4*)Wl;
#pragma unroll
        for (int it = 0; it < 9; ++it) {
            int ix = it * 512 + tid;
            if (ix < WTSH / 8) l[ix] = g[ix];
        }
        if (tid < DIMN) bias_s[tid] = bg[tid];
    }
    __syncthreads();

    int lane = tid & 63;
    int wv = tid >> 6;                 // 0..7
    int quad = lane >> 4;
    int l15 = lane & 15;
    int row0 = blockIdx.x * 256 + wv * 32;

    f32x4 acc[2][8];
#pragma unroll
    for (int s = 0; s < 2; ++s)
#pragma unroll
        for (int ct = 0; ct < 8; ++ct) acc[s][ct] = (f32x4){0.f, 0.f, 0.f, 0.f};

    for (int ks = 0; ks < 4; ++ks) {
        int kb = ks * 32 + quad * 8;
        bf16x8 ah[2];
#pragma unroll
        for (int s = 0; s < 2; ++s) {
            int r = row0 + s * 16 + l15;
            if (r > N - 1) r = N - 1;
            ah[s] = *(const bf16x8*)(A + (size_t)r * DIMN + kb);  // 16 B aligned
        }
#pragma unroll
        for (int ct = 0; ct < 8; ++ct) {
            const short* bp = Wl + (ct * 16 + l15) * KP + kb;
            bf16x8 bh = *(const bf16x8*)bp;
            bf16x8 bl = *(const bf16x8*)(bp + DIMN * KP);
#pragma unroll
            for (int s = 0; s < 2; ++s) {
                acc[s][ct] = __builtin_amdgcn_mfma_f32_16x16x32_bf16(ah[s], bh, acc[s][ct], 0, 0, 0);
                acc[s][ct] = __builtin_amdgcn_mfma_f32_16x16x32_bf16(ah[s], bl, acc[s][ct], 0, 0, 0);
            }
        }
    }

    bool doHs = (Hs != nullptr);
#pragma unroll
    for (int s = 0; s < 2; ++s) {
        int rbase = row0 + s * 16 + quad * 4;
        float ns[4];
        if (doHs) {
#pragma unroll
            for (int rj = 0; rj < 4; ++rj) {
                int row = rbase + rj;
                ns[rj] = (row < N) ? norm_s[row] : 0.f;
            }
        }
#pragma unroll
        for (int ct = 0; ct < 8; ++ct) {
            int col = ct * 16 + l15;
            float bv = bias_s[col];
#pragma unroll
            for (int rj = 0; rj < 4; ++rj) {
                int row = rbase + rj;
                if (row < N) {
                    float o = fmaxf(acc[s][ct][rj] + bv, 0.f) + Hres[(size_t)row * DIMN + col];
                    tgt[(size_t)row * DIMN + col] = o;   // plain: cache-resident for next layer
                    if (doHs) Hs[(size_t)row * DIMN + col] = f2bf(o * ns[rj]);
                }
            }
        }
    }
}

// ------- SpMM v2: uint4 gathers, 4 edges/wave concurrent, 64B/lane in flight -------
__global__ __launch_bounds__(256) void k_spmm(const uint4* __restrict__ Hs4,
                                              u64x2* __restrict__ AggB2,
                                              const int* __restrict__ csr,
                                              const int* __restrict__ rowptr,
                                              const int* __restrict__ deg,
                                              const float* __restrict__ norm_d, int N) {
    int wave = (blockIdx.x * blockDim.x + threadIdx.x) >> 6;
    int lane = threadIdx.x & 63;
    if (wave >= N) return;
    int cnt = deg[wave];
    const int* base = csr + rowptr[wave];
    int g = lane >> 4;    // edge slot 0..3
    int l4 = lane & 15;   // 16B chunk of row
    float acc[8];
#pragma unroll
    for (int j = 0; j < 8; ++j) acc[j] = 0.f;

#define ACC8(h)                                   \
    acc[0] += blo((h).x); acc[1] += bhi((h).x);   \
    acc[2] += blo((h).y); acc[3] += bhi((h).y);   \
    acc[4] += blo((h).z); acc[5] += bhi((h).z);   \
    acc[6] += blo((h).w); acc[7] += bhi((h).w);

    int e = 0;
    for (; e + 16 <= cnt; e += 16) {   // 4 x 16B in flight per lane
        int s0 = base[e + g];
        int s1 = base[e + 4 + g];
        int s2 = base[e + 8 + g];
        int s3 = base[e + 12 + g];
        uint4 h0 = Hs4[(size_t)s0 * 16 + l4];
        uint4 h1 = Hs4[(size_t)s1 * 16 + l4];
        uint4 h2 = Hs4[(size_t)s2 * 16 + l4];
        uint4 h3 = Hs4[(size_t)s3 * 16 + l4];
        ACC8(h0) ACC8(h1) ACC8(h2) ACC8(h3)
    }
    for (; e + 8 <= cnt; e += 8) {
        int s0 = base[e + g];
        int s1 = base[e + 4 + g];
        uint4 h0 = Hs4[(size_t)s0 * 16 + l4];
        uint4 h1 = Hs4[(size_t)s1 * 16 + l4];
        ACC8(h0) ACC8(h1)
    }
    for (; e < cnt; e += 4) {          // predicated tail, 4 edges/iter
        int ee = e + g;
        int sc = base[min(ee, cnt - 1)];
        uint4 hv = Hs4[(size_t)sc * 16 + l4];
        if (ee < cnt) { ACC8(hv) }
    }
#undef ACC8

    // reduce across the 4 edge-slot groups (lanes with equal l4)
#pragma unroll
    for (int j = 0; j < 8; ++j) {
        acc[j] += __shfl_xor(acc[j], 16);
        acc[j] += __shfl_xor(acc[j], 32);
    }
    if (g == 0) {
        float nd = norm_d[wave];
        unsigned u0 = pack2(acc[0] * nd, acc[1] * nd);
        unsigned u1 = pack2(acc[2] * nd, acc[3] * nd);
        unsigned u2 = pack2(acc[4] * nd, acc[5] * nd);
        unsigned u3 = pack2(acc[6] * nd, acc[7] * nd);
        u64x2 o;
        o[0] = (unsigned long long)u0 | ((unsigned long long)u1 << 32);
        o[1] = (unsigned long long)u2 | ((unsigned long long)u3 << 32);
        AggB2[(size_t)wave * 16 + l4] = o;   // plain: keep AggB in L2/L3 for the GEMM
    }
}

static inline char* align256(char* p) {
    return (char*)(((uintptr_t)p + 255) & ~(uintptr_t)255);
}

extern "C" void kernel_launch(void* const* d_in, const int* in_sizes, int n_in,
                              void* d_out, int out_size, void* d_ws, size_t ws_size,
                              hipStream_t stream) {
    const float* h_in = (const float*)d_in[0];
    const int* src = (const int*)d_in[1];
    const int* dst = (const int*)d_in[2];
    const float* W_embed = (const float*)d_in[3];
    const float* b_embed = (const float*)d_in[4];
    const float* Ws = (const float*)d_in[5];
    const float* bs = (const float*)d_in[6];
    float* out = (float*)d_out;

    const int N = in_sizes[0] / DIMN;  // 100000
    const int E = in_sizes[1];         // 1600000
    const int W = (N + 1) / 2;         // packed degOut words
    const int NBUK = (N + BUCKW - 1) >> BQL;  // 196

    // -------- workspace carve --------
    char* w = (char*)d_ws;
    float* Hc = (float*)w;               w = align256(w + (size_t)N * DIMN * 4);
    unsigned short* AggB = (unsigned short*)w; w = align256(w + (size_t)N * DIMN * 2);
    unsigned short* Hs = (unsigned short*)w;   w = align256(w + (size_t)N * DIMN * 2);
    int2* pairs = (int2*)w;              w = align256(w + (size_t)NBUK * BUCKCAP * 8);
    int* csr = (int*)w;                  w = align256(w + (size_t)NBUK * BUCKCAP * 4);
    int* rowptr = (int*)w;               w = align256(w + (size_t)N * 4);
    int* deg = (int*)w;                  w = align256(w + (size_t)N * 4);
    int* gcur = (int*)w;                 w = align256(w + (size_t)NBUK * 4);
    unsigned int* degOutP = (unsigned int*)w;  w = align256(w + (size_t)HP_C * W * 4);
    float* norm_s = (float*)w;           w = align256(w + (size_t)N * 4);
    float* norm_d = (float*)w;           w = align256(w + (size_t)N * 4);
    short* wt = (short*)w;               w = align256(w + (size_t)5 * WTSH * 2);

    (void)hipMemsetAsync(gcur, 0, (size_t)NBUK * 4, stream);

    int gb = (N + 255) / 256;            // 391 (512-thread GEMM blocks, 256 rows each)
    int nb = (W + 255) / 256;
    int bb = (E + BSCH - 1) / BSCH;      // 391

    // degOut histogram partials (no atomic flush) + weight prep, role-split
    k_pre<<<HIST_BLOCKS + 5, 256, 0, stream>>>(src, W_embed, Ws, degOutP, wt, N, E);

    // binned counting-sort CSR
    k_binsort<<<bb, 256, 0, stream>>>(src, dst, gcur, pairs, E, NBUK);
    k_build<<<NBUK, 256, 0, stream>>>(pairs, gcur, csr, rowptr, deg, N);

    // norms (deg from build; degOut from histogram partials)
    k_norms<<<nb, 256, 0, stream>>>(deg, degOutP, norm_d, norm_s, N);

    // embed GEMM with fused Hs=bf16(Hc*norm_s) epilogue
    k_gemm_f32<<<gb, 512, 0, stream>>>(h_in, wt, b_embed, Hc, norm_s, Hs, N);

    // layers
    int sb = (N + 3) / 4;
    for (int l = 0; l < NLAYERS; ++l) {
        k_spmm<<<sb, 256, 0, stream>>>((const uint4*)Hs, (u64x2*)AggB, csr, rowptr, deg, norm_d, N);
        float* tgt = (l == NLAYERS - 1) ? out : Hc;
        unsigned short* hs_next = (l == NLAYERS - 1) ? (unsigned short*)nullptr : Hs;
        k_gemm_bf<<<gb, 512, 0, stream>>>(AggB, wt + (size_t)(l + 1) * WTSH,
                                          bs + (size_t)l * DIMN, Hc, tgt, norm_s, hs_next, N);
    }
}